// Round 14
// baseline (21.349 us; speedup 1.0000x reference)
//
#include <hip/hip_runtime.h>
#include <math.h>

#define SEARCH 7
#define PAD 3
#define S2 49
#define KNN 7
#define NCLASSES 20
#define H 64
#define W 2048
#define NPTS 131072
#define NTILES 32
#define TROWS 70                 /* rows -3..66 (zero-padded) */
#define TCOLS 70                 /* cols -3..66 (circular)    */
#define SPT 32                   /* sub-blocks per tile */
#define SLICE (NPTS / SPT)       /* 4096 points scanned per block */
#define KBLOCK 256
#define PPB 128                  /* points per pair-group chain */
#define QCAP 512

// f64-packed key: bits = (1<<62) | (distbits<<6) | j ; positive normal doubles,
// value order == bit order == exact lex-(dist, j) order (R9-proven).
#define SENTINEL_BITS 0x7FE0000000000000ull
#define CUTOFF_KEYMAX 0x4000000FE000003Full   /* (1<<62)|(0x3f800000<<6)|63 */

struct InvG { float v[S2]; };

// min/max bubble insert into sorted doubles sP0..sP6 (13 f64 ops, keys unique)
#define INSF_P(P, KEY) do {                                             \
    double _x = (KEY);                                                  \
    double _t;                                                          \
    _t = fmin(s##P##0, _x); _x = fmax(s##P##0, _x); s##P##0 = _t;       \
    _t = fmin(s##P##1, _x); _x = fmax(s##P##1, _x); s##P##1 = _t;       \
    _t = fmin(s##P##2, _x); _x = fmax(s##P##2, _x); s##P##2 = _t;       \
    _t = fmin(s##P##3, _x); _x = fmax(s##P##3, _x); s##P##3 = _t;       \
    _t = fmin(s##P##4, _x); _x = fmax(s##P##4, _x); s##P##4 = _t;       \
    _t = fmin(s##P##5, _x); _x = fmax(s##P##5, _x); s##P##5 = _t;       \
    s##P##6 = fmin(s##P##6, _x);                                        \
} while (0)

// one candidate j for BOTH points: independent chains interleave for ILP
#define CAND2(J, DX) do {                                               \
    float nbA = ftile[rbA + (DX)];                                      \
    float nbB = ftile[rbB + (DX)];                                      \
    nbA = (nbA < 0.0f) ? __builtin_inff() : nbA;                        \
    nbB = (nbB < 0.0f) ? __builtin_inff() : nbB;                        \
    float ig = invg.v[J];                                               \
    float dA = fabsf(nbA - uA) * ig;                                    \
    float dB = fabsf(nbB - uB) * ig;                                    \
    unsigned long long kA = (1ull << 62)                                \
        | ((unsigned long long)__float_as_uint(dA) << 6) | (unsigned)(J);\
    unsigned long long kB = (1ull << 62)                                \
        | ((unsigned long long)__float_as_uint(dB) << 6) | (unsigned)(J);\
    INSF_P(A, __longlong_as_double((long long)kA));                     \
    INSF_P(B, __longlong_as_double((long long)kB));                     \
} while (0)

__global__ __launch_bounds__(KBLOCK, 4) void knn_kernel(
    const float* __restrict__ proj_range,
    const float* __restrict__ unproj_range,
    const int* __restrict__ proj_argmax,
    const int* __restrict__ pxv,
    const int* __restrict__ pyv,
    int* __restrict__ outv,
    InvG invg)
{
    __shared__ float  ftile[TROWS * TCOLS];
    __shared__ double kbufA[PPB][KNN];
    __shared__ double kbufB[PPB][KNN];
    __shared__ unsigned queue[QCAP];
    __shared__ int qcnt;

    const int tid  = threadIdx.x;
    const int t    = blockIdx.x >> 5;        // tile
    const int sub  = blockIdx.x & 31;        // slice
    const int tbase = t << 6;
    const int lane = tid & 63;
    const int wave = tid >> 6;               // 0..3

    if (tid == 0) qcnt = 0;

    // stage 70x70 padded range tile (classes gathered from L2 in epilogue)
#pragma unroll
    for (int it = 0; it < 18; ++it) {
        int r = it * 4 + wave;
        if (r < TROWS) {
            int sr = r - 3;
            bool vr = (unsigned)sr < (unsigned)H;
            int gb = (vr ? sr : 0) * W;
            int ca = (tbase - 3 + lane) & (W - 1);
            float fv = proj_range[gb + ca];
            ftile[r * TCOLS + lane] = vr ? fv : 0.0f;
            if (lane < TCOLS - 64) {
                int cb = (tbase - 3 + 64 + lane) & (W - 1);
                float fv2 = proj_range[gb + cb];
                ftile[r * TCOLS + 64 + lane] = vr ? fv2 : 0.0f;
            }
        }
    }
    __syncthreads();                          // tile ready, qcnt=0 visible

    // scan own slice of px; enqueue matches (px>>6 == t)  (R8/R9-proven)
    {
        const int4* px4 = (const int4*)pxv;
        int base4 = (sub * SLICE) >> 2;
#pragma unroll
        for (int k = 0; k < 4; ++k) {
            int idx4 = base4 + k * KBLOCK + tid;
            int4 v = px4[idx4];
            int i0x = idx4 * 4;
#pragma unroll
            for (int e = 0; e < 4; ++e) {
                int x = (e == 0) ? v.x : (e == 1) ? v.y : (e == 2) ? v.z : v.w;
                if ((x >> 6) == t) {
                    int i = i0x + e;
                    int y = pyv[i];
                    int pos = atomicAdd(&qcnt, 1);
                    if (pos < QCAP)
                        queue[pos] = (unsigned)i | ((unsigned)(x & 63) << 17)
                                                | ((unsigned)y << 23);
                }
            }
        }
    }
    __syncthreads();
    const int count = min(qcnt, QCAP);

    const int pairp = wave >> 1;             // 0..1
    const int role  = wave & 1;              // wave-uniform
    const int pidx  = pairp * 64 + lane;     // 0..127

    for (int base = 0; base < count; base += 2 * PPB) {
        int slotA = base + pidx;
        int slotB = base + PPB + pidx;
        bool activeA = slotA < count;
        bool activeB = slotB < count;        // activeB implies activeA
        bool anyact = __ballot(activeA) != 0;

        if (anyact) {
            unsigned pkA = activeA ? queue[slotA] : 0u;
            unsigned pkB = activeB ? queue[slotB] : 0u;
            int iA = (int)(pkA & 0x1FFFFu), iB = (int)(pkB & 0x1FFFFu);
            int xlA = (int)((pkA >> 17) & 63u), xlB = (int)((pkB >> 17) & 63u);
            int yA = (int)((pkA >> 23) & 63u), yB = (int)((pkB >> 23) & 63u);
            float uA = unproj_range[iA];
            float uB = unproj_range[iB];

            const double sent = __longlong_as_double((long long)SENTINEL_BITS);
            double sA0 = sent, sA1 = sent, sA2 = sent, sA3 = sent,
                   sA4 = sent, sA5 = sent, sA6 = sent;
            double sB0 = sent, sB1 = sent, sB2 = sent, sB3 = sent,
                   sB4 = sent, sB5 = sent, sB6 = sent;

            if (role == 0) {
                // j = 0..23 : rows dy=-3..-1 full, dy=0 dx=-3..-1 (proven split)
#pragma unroll
                for (int dy = -3; dy <= 0; ++dy) {
                    int rbA = (yA + dy + 3) * TCOLS + xlA + 3;
                    int rbB = (yB + dy + 3) * TCOLS + xlB + 3;
                    const int dxmax = (dy == 0) ? -1 : 3;
#pragma unroll
                    for (int dx = -3; dx <= dxmax; ++dx) {
                        const int j = (dy + 3) * 7 + (dx + 3);
                        CAND2(j, dx);
                    }
                }
            } else {
                const double ckey =
                    __longlong_as_double((long long)((1ull << 62) | 24ull));
                INSF_P(A, ckey);
                INSF_P(B, ckey);
#pragma unroll
                for (int dy = 0; dy <= 3; ++dy) {
                    int rbA = (yA + dy + 3) * TCOLS + xlA + 3;
                    int rbB = (yB + dy + 3) * TCOLS + xlB + 3;
                    const int dxmin = (dy == 0) ? 1 : -3;
#pragma unroll
                    for (int dx = dxmin; dx <= 3; ++dx) {
                        const int j = (dy + 3) * 7 + (dx + 3);
                        CAND2(j, dx);
                    }
                }
                kbufA[pidx][0] = sA0; kbufA[pidx][1] = sA1; kbufA[pidx][2] = sA2;
                kbufA[pidx][3] = sA3; kbufA[pidx][4] = sA4; kbufA[pidx][5] = sA5;
                kbufA[pidx][6] = sA6;
                kbufB[pidx][0] = sB0; kbufB[pidx][1] = sB1; kbufB[pidx][2] = sB2;
                kbufB[pidx][3] = sB3; kbufB[pidx][4] = sB4; kbufB[pidx][5] = sB5;
                kbufB[pidx][6] = sB6;
            }
            if (role == 0) {
                __syncthreads();
                const double cutmax = __longlong_as_double((long long)CUTOFF_KEYMAX);

                // ---- epilogue for a point: merge + class gather + vote + store
#define EPILOG(P) do {                                                   \
                double m0 = fmin(s##P##0, kbuf##P[pidx][6]);             \
                double m1 = fmin(s##P##1, kbuf##P[pidx][5]);             \
                double m2 = fmin(s##P##2, kbuf##P[pidx][4]);             \
                double m3 = fmin(s##P##3, kbuf##P[pidx][3]);             \
                double m4 = fmin(s##P##4, kbuf##P[pidx][2]);             \
                double m5 = fmin(s##P##5, kbuf##P[pidx][1]);             \
                double m6 = fmin(s##P##6, kbuf##P[pidx][0]);             \
                int c0, c1, c2, c3, c4, c5, c6;                          \
                int yP = y##P, xlP = xl##P;                              \
                {                                                        \
                  long long kb; int j, dy7, sr, src, colw; bool sel, vrow;\
                  kb = __double_as_longlong(m0); j = (int)(kb & 63);     \
                  sel = m0 <= cutmax; dy7 = (j * 37) >> 8; sr = yP + dy7 - 3;\
                  vrow = (unsigned)sr < (unsigned)H; src = min(max(sr,0),H-1);\
                  colw = (tbase - 3 + xlP + (j - dy7 * 7)) & (W - 1);    \
                  c0 = (sel && vrow) ? proj_argmax[src * W + colw] : 0;  \
                  kb = __double_as_longlong(m1); j = (int)(kb & 63);     \
                  sel = m1 <= cutmax; dy7 = (j * 37) >> 8; sr = yP + dy7 - 3;\
                  vrow = (unsigned)sr < (unsigned)H; src = min(max(sr,0),H-1);\
                  colw = (tbase - 3 + xlP + (j - dy7 * 7)) & (W - 1);    \
                  c1 = (sel && vrow) ? proj_argmax[src * W + colw] : 0;  \
                  kb = __double_as_longlong(m2); j = (int)(kb & 63);     \
                  sel = m2 <= cutmax; dy7 = (j * 37) >> 8; sr = yP + dy7 - 3;\
                  vrow = (unsigned)sr < (unsigned)H; src = min(max(sr,0),H-1);\
                  colw = (tbase - 3 + xlP + (j - dy7 * 7)) & (W - 1);    \
                  c2 = (sel && vrow) ? proj_argmax[src * W + colw] : 0;  \
                  kb = __double_as_longlong(m3); j = (int)(kb & 63);     \
                  sel = m3 <= cutmax; dy7 = (j * 37) >> 8; sr = yP + dy7 - 3;\
                  vrow = (unsigned)sr < (unsigned)H; src = min(max(sr,0),H-1);\
                  colw = (tbase - 3 + xlP + (j - dy7 * 7)) & (W - 1);    \
                  c3 = (sel && vrow) ? proj_argmax[src * W + colw] : 0;  \
                  kb = __double_as_longlong(m4); j = (int)(kb & 63);     \
                  sel = m4 <= cutmax; dy7 = (j * 37) >> 8; sr = yP + dy7 - 3;\
                  vrow = (unsigned)sr < (unsigned)H; src = min(max(sr,0),H-1);\
                  colw = (tbase - 3 + xlP + (j - dy7 * 7)) & (W - 1);    \
                  c4 = (sel && vrow) ? proj_argmax[src * W + colw] : 0;  \
                  kb = __double_as_longlong(m5); j = (int)(kb & 63);     \
                  sel = m5 <= cutmax; dy7 = (j * 37) >> 8; sr = yP + dy7 - 3;\
                  vrow = (unsigned)sr < (unsigned)H; src = min(max(sr,0),H-1);\
                  colw = (tbase - 3 + xlP + (j - dy7 * 7)) & (W - 1);    \
                  c5 = (sel && vrow) ? proj_argmax[src * W + colw] : 0;  \
                  kb = __double_as_longlong(m6); j = (int)(kb & 63);     \
                  sel = m6 <= cutmax; dy7 = (j * 37) >> 8; sr = yP + dy7 - 3;\
                  vrow = (unsigned)sr < (unsigned)H; src = min(max(sr,0),H-1);\
                  colw = (tbase - 3 + xlP + (j - dy7 * 7)) & (W - 1);    \
                  c6 = (sel && vrow) ? proj_argmax[src * W + colw] : 0;  \
                }                                                        \
                int n0 = 1, n1 = 1, n2 = 1, n3 = 1, n4 = 1, n5 = 1, n6 = 1;\
                { bool e;                                                \
                  e = (c0==c1); n0+=e; n1+=e;  e = (c0==c2); n0+=e; n2+=e;\
                  e = (c0==c3); n0+=e; n3+=e;  e = (c0==c4); n0+=e; n4+=e;\
                  e = (c0==c5); n0+=e; n5+=e;  e = (c0==c6); n0+=e; n6+=e;\
                  e = (c1==c2); n1+=e; n2+=e;  e = (c1==c3); n1+=e; n3+=e;\
                  e = (c1==c4); n1+=e; n4+=e;  e = (c1==c5); n1+=e; n5+=e;\
                  e = (c1==c6); n1+=e; n6+=e;  e = (c2==c3); n2+=e; n3+=e;\
                  e = (c2==c4); n2+=e; n4+=e;  e = (c2==c5); n2+=e; n5+=e;\
                  e = (c2==c6); n2+=e; n6+=e;  e = (c3==c4); n3+=e; n4+=e;\
                  e = (c3==c5); n3+=e; n5+=e;  e = (c3==c6); n3+=e; n6+=e;\
                  e = (c4==c5); n4+=e; n5+=e;  e = (c4==c6); n4+=e; n6+=e;\
                  e = (c5==c6); n5+=e; n6+=e; }                          \
                int best = 0;                                            \
                { int sc; bool valid;                                    \
                  valid = (unsigned)(c0-1) < (unsigned)(NCLASSES-1);     \
                  sc = valid ? ((n0<<5)|(31-c0)) : 0; best = max(best, sc);\
                  valid = (unsigned)(c1-1) < (unsigned)(NCLASSES-1);     \
                  sc = valid ? ((n1<<5)|(31-c1)) : 0; best = max(best, sc);\
                  valid = (unsigned)(c2-1) < (unsigned)(NCLASSES-1);     \
                  sc = valid ? ((n2<<5)|(31-c2)) : 0; best = max(best, sc);\
                  valid = (unsigned)(c3-1) < (unsigned)(NCLASSES-1);     \
                  sc = valid ? ((n3<<5)|(31-c3)) : 0; best = max(best, sc);\
                  valid = (unsigned)(c4-1) < (unsigned)(NCLASSES-1);     \
                  sc = valid ? ((n4<<5)|(31-c4)) : 0; best = max(best, sc);\
                  valid = (unsigned)(c5-1) < (unsigned)(NCLASSES-1);     \
                  sc = valid ? ((n5<<5)|(31-c5)) : 0; best = max(best, sc);\
                  valid = (unsigned)(c6-1) < (unsigned)(NCLASSES-1);     \
                  sc = valid ? ((n6<<5)|(31-c6)) : 0; best = max(best, sc); }\
                if (active##P) {                                         \
                    int res = (best == 0) ? 1 : (31 - (best & 31));      \
                    __builtin_nontemporal_store(res, &outv[i##P]);       \
                }                                                        \
            } while (0)

                EPILOG(A);
                if (__ballot(activeB) != 0) EPILOG(B);
#undef EPILOG
                __syncthreads();             // matches role-1's barriers below
            } else {
                __syncthreads();
                __syncthreads();
            }
        } else {
            __syncthreads();
            __syncthreads();
        }
    }
}

extern "C" void kernel_launch(void* const* d_in, const int* in_sizes, int n_in,
                              void* d_out, int out_size, void* d_ws, size_t ws_size,
                              hipStream_t stream) {
    const float* proj_range   = (const float*)d_in[0];
    const float* unproj_range = (const float*)d_in[1];
    const int*   proj_argmax  = (const int*)d_in[2];
    const int*   px           = (const int*)d_in[3];
    const int*   py           = (const int*)d_in[4];
    int* out = (int*)d_out;

    // Emulate numpy float32 pipeline for the inverse-gaussian table.
    InvG invg;
    float g[S2];
    for (int yy = 0; yy < SEARCH; ++yy) {
        for (int xx = 0; xx < SEARCH; ++xx) {
            float fdx = (float)xx - 3.0f;
            float fdy = (float)yy - 3.0f;
            float s   = fdx * fdx + fdy * fdy;
            float arg = -s / 2.0f;
            float e   = (float)exp((double)arg);
            float gg  = e / 6.2831855f;
            g[yy * SEARCH + xx] = gg;
        }
    }
    float r[8];
    for (int tt = 0; tt < 8; ++tt) r[tt] = g[tt];
    int ii;
    for (ii = 8; ii + 8 <= 48; ii += 8)
        for (int tt = 0; tt < 8; ++tt) r[tt] += g[ii + tt];
    float ssum = ((r[0] + r[1]) + (r[2] + r[3])) + ((r[4] + r[5]) + (r[6] + r[7]));
    for (; ii < S2; ++ii) ssum += g[ii];
    for (int tt = 0; tt < S2; ++tt) invg.v[tt] = 1.0f - (g[tt] / ssum);

    knn_kernel<<<NTILES * SPT, KBLOCK, 0, stream>>>(
        proj_range, unproj_range, proj_argmax, px, py, out, invg);
}

// Round 15
// 19.802 us; speedup vs baseline: 1.0781x; 1.0781x over previous
//
#include <hip/hip_runtime.h>
#include <math.h>

#define SEARCH 7
#define PAD 3
#define S2 49
#define KNN 7
#define NCLASSES 20
#define H 64
#define W 2048
#define NPTS 131072
#define NTILES 32
#define TROWS 70                 /* rows -3..66 (zero-padded) */
#define TCOLS 70                 /* cols -3..66 (circular)    */
#define SPT 32                   /* sub-blocks per tile */
#define SLICE (NPTS / SPT)       /* 4096 points scanned per block */
#define KBLOCK 256
#define QCAP 512

// f64-packed key: bits = (1<<62) | (distbits<<6) | j ; positive normal doubles,
// value order == bit order == exact lex-(dist, j) order (R9-proven).
#define SENTINEL_BITS 0x7FE0000000000000ull
#define CUTOFF_KEYMAX 0x4000000FE000003Full   /* (1<<62)|(0x3f800000<<6)|63 */

struct InvG { float v[S2]; };

// min/max bubble insert into sorted doubles s0..s6 (13 f64 ops, keys unique)
#define INSF(KEY) do {                                                  \
    double _x = (KEY);                                                  \
    double _t;                                                          \
    _t = fmin(s0, _x); _x = fmax(s0, _x); s0 = _t;                      \
    _t = fmin(s1, _x); _x = fmax(s1, _x); s1 = _t;                      \
    _t = fmin(s2, _x); _x = fmax(s2, _x); s2 = _t;                      \
    _t = fmin(s3, _x); _x = fmax(s3, _x); s3 = _t;                      \
    _t = fmin(s4, _x); _x = fmax(s4, _x); s4 = _t;                      \
    _t = fmin(s5, _x); _x = fmax(s5, _x); s5 = _t;                      \
    s6 = fmin(s6, _x);                                                  \
} while (0)

#define CAND(J, RB, DX) do {                                            \
    float nb = ftile[(RB) + (DX)];                                      \
    nb = (nb < 0.0f) ? __builtin_inff() : nb;                           \
    float d = fabsf(nb - u) * invg.v[J];                                \
    unsigned long long kb = (1ull << 62)                                \
        | ((unsigned long long)__float_as_uint(d) << 6)                 \
        | (unsigned)(J);                                                \
    INSF(__longlong_as_double((long long)kb));                          \
} while (0)

__global__ __launch_bounds__(KBLOCK, 4) void knn_kernel(
    const float* __restrict__ proj_range,
    const float* __restrict__ unproj_range,
    const int* __restrict__ proj_argmax,
    const int* __restrict__ pxv,
    const int* __restrict__ pyv,
    int* __restrict__ outv,
    InvG invg)
{
    __shared__ float  ftile[TROWS * TCOLS];
    __shared__ unsigned queue[QCAP];
    __shared__ int qcnt;

    const int tid  = threadIdx.x;
    const int t    = blockIdx.x >> 5;        // tile
    const int sub  = blockIdx.x & 31;        // slice
    const int tbase = t << 6;
    const int lane = tid & 63;
    const int wave = tid >> 6;               // 0..3

    if (tid == 0) qcnt = 0;

    // stage 70x70 padded range tile (classes gathered from L2 in epilogue)
#pragma unroll
    for (int it = 0; it < 18; ++it) {
        int r = it * 4 + wave;
        if (r < TROWS) {
            int sr = r - 3;
            bool vr = (unsigned)sr < (unsigned)H;
            int gb = (vr ? sr : 0) * W;
            int ca = (tbase - 3 + lane) & (W - 1);
            float fv = proj_range[gb + ca];
            ftile[r * TCOLS + lane] = vr ? fv : 0.0f;
            if (lane < TCOLS - 64) {
                int cb = (tbase - 3 + 64 + lane) & (W - 1);
                float fv2 = proj_range[gb + cb];
                ftile[r * TCOLS + 64 + lane] = vr ? fv2 : 0.0f;
            }
        }
    }
    __syncthreads();                          // tile ready, qcnt=0 visible

    // scan own slice of px; enqueue matches (px>>6 == t)  (R8/R9-proven)
    {
        const int4* px4 = (const int4*)pxv;
        int base4 = (sub * SLICE) >> 2;
#pragma unroll
        for (int k = 0; k < 4; ++k) {
            int idx4 = base4 + k * KBLOCK + tid;
            int4 v = px4[idx4];
            int i0x = idx4 * 4;
#pragma unroll
            for (int e = 0; e < 4; ++e) {
                int x = (e == 0) ? v.x : (e == 1) ? v.y : (e == 2) ? v.z : v.w;
                if ((x >> 6) == t) {
                    int i = i0x + e;
                    int y = pyv[i];
                    int pos = atomicAdd(&qcnt, 1);
                    if (pos < QCAP)
                        queue[pos] = (unsigned)i | ((unsigned)(x & 63) << 17)
                                                | ((unsigned)y << 23);
                }
            }
        }
    }
    __syncthreads();                          // queue ready; LAST barrier
    const int count = min(qcnt, QCAP);

    // one thread = one point, full 49-candidate chain, no further barriers
    for (int slot = tid; slot < count; slot += KBLOCK) {
        unsigned pk = queue[slot];
        int i  = (int)(pk & 0x1FFFFu);
        int xl = (int)((pk >> 17) & 63u);
        int y  = (int)((pk >> 23) & 63u);
        float u = unproj_range[i];

        const double sent = __longlong_as_double((long long)SENTINEL_BITS);
        double s0 = sent, s1 = sent, s2 = sent, s3 = sent,
               s4 = sent, s5 = sent, s6 = sent;

        INSF(__longlong_as_double((long long)((1ull << 62) | 24ull)));  // center

#pragma unroll
        for (int dy = -3; dy <= 3; ++dy) {
            int rb = (y + dy + 3) * TCOLS + xl + 3;
#pragma unroll
            for (int dx = -3; dx <= 3; ++dx) {
                const int j = (dy + 3) * 7 + (dx + 3);
                if (j == 24) continue;        // center handled above
                CAND(j, rb, dx);
            }
        }

        const double cutmax = __longlong_as_double((long long)CUTOFF_KEYMAX);
        int c0, c1, c2, c3, c4, c5, c6;
        // winner classes gathered from global proj_argmax (L2-hot);
        // zero-pad rows -> class 0; circular in W (R13-proven pattern)
#define CLSK(MK, CK) do {                                                \
        long long kb = __double_as_longlong(MK);                         \
        int j = (int)(kb & 63);                                          \
        bool sel = (MK) <= cutmax;                                       \
        int dy7 = (j * 37) >> 8;                                         \
        int sr = y + dy7 - 3;                                            \
        bool vrow = (unsigned)sr < (unsigned)H;                          \
        int src = min(max(sr, 0), H - 1);                                \
        int colw = (tbase - 3 + xl + (j - dy7 * 7)) & (W - 1);           \
        int cc = proj_argmax[src * W + colw];                            \
        CK = (sel && vrow) ? cc : 0;                                     \
    } while (0)
        CLSK(s0, c0); CLSK(s1, c1); CLSK(s2, c2); CLSK(s3, c3);
        CLSK(s4, c4); CLSK(s5, c5); CLSK(s6, c6);
#undef CLSK

        int n0 = 1, n1 = 1, n2 = 1, n3 = 1, n4 = 1, n5 = 1, n6 = 1;
#define PAIRV(A, B) do { bool e = (c##A == c##B); n##A += e ? 1 : 0; n##B += e ? 1 : 0; } while (0)
        PAIRV(0,1); PAIRV(0,2); PAIRV(0,3); PAIRV(0,4); PAIRV(0,5); PAIRV(0,6);
        PAIRV(1,2); PAIRV(1,3); PAIRV(1,4); PAIRV(1,5); PAIRV(1,6);
        PAIRV(2,3); PAIRV(2,4); PAIRV(2,5); PAIRV(2,6);
        PAIRV(3,4); PAIRV(3,5); PAIRV(3,6);
        PAIRV(4,5); PAIRV(4,6);
        PAIRV(5,6);
#undef PAIRV

        int best = 0;
#define SCORE(K) do {                                                    \
        bool valid = (unsigned)(c##K - 1) < (unsigned)(NCLASSES - 1);    \
        int sc = valid ? ((n##K << 5) | (31 - c##K)) : 0;                \
        best = max(best, sc);                                            \
    } while (0)
        SCORE(0); SCORE(1); SCORE(2); SCORE(3); SCORE(4); SCORE(5); SCORE(6);
#undef SCORE
        int res = (best == 0) ? 1 : (31 - (best & 31));
        __builtin_nontemporal_store(res, &outv[i]);
    }
}

extern "C" void kernel_launch(void* const* d_in, const int* in_sizes, int n_in,
                              void* d_out, int out_size, void* d_ws, size_t ws_size,
                              hipStream_t stream) {
    const float* proj_range   = (const float*)d_in[0];
    const float* unproj_range = (const float*)d_in[1];
    const int*   proj_argmax  = (const int*)d_in[2];
    const int*   px           = (const int*)d_in[3];
    const int*   py           = (const int*)d_in[4];
    int* out = (int*)d_out;

    // Emulate numpy float32 pipeline for the inverse-gaussian table.
    InvG invg;
    float g[S2];
    for (int yy = 0; yy < SEARCH; ++yy) {
        for (int xx = 0; xx < SEARCH; ++xx) {
            float fdx = (float)xx - 3.0f;
            float fdy = (float)yy - 3.0f;
            float s   = fdx * fdx + fdy * fdy;
            float arg = -s / 2.0f;
            float e   = (float)exp((double)arg);
            float gg  = e / 6.2831855f;
            g[yy * SEARCH + xx] = gg;
        }
    }
    float r[8];
    for (int tt = 0; tt < 8; ++tt) r[tt] = g[tt];
    int ii;
    for (ii = 8; ii + 8 <= 48; ii += 8)
        for (int tt = 0; tt < 8; ++tt) r[tt] += g[ii + tt];
    float ssum = ((r[0] + r[1]) + (r[2] + r[3])) + ((r[4] + r[5]) + (r[6] + r[7]));
    for (; ii < S2; ++ii) ssum += g[ii];
    for (int tt = 0; tt < S2; ++tt) invg.v[tt] = 1.0f - (g[tt] / ssum);

    knn_kernel<<<NTILES * SPT, KBLOCK, 0, stream>>>(
        proj_range, unproj_range, proj_argmax, px, py, out, invg);
}